// Round 2
// baseline (1048.662 us; speedup 1.0000x reference)
//
#include <hip/hip_runtime.h>
#include <hip/hip_cooperative_groups.h>
#include <math.h>

namespace cg = cooperative_groups;

#define V 50257
#define E 1024
#define H 1024
#define L 512
#define NBLK 1024

// d_out offsets (floats): [log_probs V][h_new H][attn_weights L]
#define OUT_H  50257
#define OUT_AW 51281

// ws offsets (floats)
#define WS_S    0       // 512 attn scores
#define WS_X    1024    // 2048 x = [embedded, attn_applied]
#define WS_GH   3072    // 3072
#define WS_GI   6144    // 3072
#define WS_HN   9216    // 1024 h_new
#define WS_BM   10240   // 1024 per-block maxes
#define WS_BS   11264   // 1024 per-block sumexps
#define WS_OFF  12288   // logsumexp offset

__device__ __forceinline__ float dot4(const float4 a, const float4 b) {
    return a.x * b.x + a.y * b.y + a.z * b.z + a.w * b.w;
}

__device__ __forceinline__ float wave_sum(float v) {
    for (int off = 32; off > 0; off >>= 1) v += __shfl_down(v, off, 64);
    return v;
}

__global__ __launch_bounds__(256, 4)
void mega(const int* __restrict__ input,
          const float* __restrict__ hidden,
          const float* __restrict__ enc,
          const float* __restrict__ emb_table,
          const float* __restrict__ attn_W,
          const float* __restrict__ attn_b,
          const float* __restrict__ W_ih,
          const float* __restrict__ W_hh,
          const float* __restrict__ b_ih,
          const float* __restrict__ b_hh,
          const float* __restrict__ out_W,
          const float* __restrict__ out_b,
          float* __restrict__ out,
          float* __restrict__ ws) {
    cg::grid_group grid = cg::this_grid();
    __shared__ float smem[1040];
    const int t = threadIdx.x;
    const int lane = t & 63;
    const int wid = t >> 6;
    const int gwave = blockIdx.x * 4 + wid;
    const float4* h4 = (const float4*)hidden;
    const float* embrow = emb_table + (size_t)input[0] * E;
    const float4* emb4 = (const float4*)embrow;

    // ---- S1: attn scores (waves 0..511) + gh rows (512..3583) + housekeeping ----
    if (gwave < L) {
        const float4* w4 = (const float4*)(attn_W + (size_t)gwave * (E + H));
        float acc = 0.f;
        for (int i = lane; i < (E + H) / 4; i += 64) {
            float4 a = (i < E / 4) ? emb4[i] : h4[i - E / 4];
            acc += dot4(a, w4[i]);
        }
        acc = wave_sum(acc);
        if (lane == 0) ws[WS_S + gwave] = acc + attn_b[gwave];
    } else if (gwave < L + 3 * H) {
        int k = gwave - L;
        const float4* w4 = (const float4*)(W_hh + (size_t)k * H);
        float acc = 0.f;
        for (int i = lane; i < H / 4; i += 64) acc += dot4(h4[i], w4[i]);
        acc = wave_sum(acc);
        if (lane == 0) ws[WS_GH + k] = acc + b_hh[k];
    } else if (gwave < 3600) {           // zero attn_applied accumulator
        ws[WS_X + E + (gwave - 3584) * 64 + lane] = 0.f;
    } else if (gwave < 3616) {           // stage embedded into x
        int i = (gwave - 3600) * 64 + lane;
        ws[WS_X + i] = embrow[i];
    }
    grid.sync();

    // ---- S2+S3: redundant per-block softmax + attn_applied slice (blocks 0..31) ----
    if (blockIdx.x < 32) {
        float v0 = ws[WS_S + t];
        float v1 = ws[WS_S + t + 256];
        float m = fmaxf(v0, v1);
        for (int off = 32; off > 0; off >>= 1) m = fmaxf(m, __shfl_down(m, off, 64));
        if (lane == 0) smem[512 + wid] = m;
        __syncthreads();
        if (t == 0)
            smem[520] = fmaxf(fmaxf(smem[512], smem[513]), fmaxf(smem[514], smem[515]));
        __syncthreads();
        float bm = smem[520];
        float e0 = expf(v0 - bm), e1 = expf(v1 - bm);
        float s = wave_sum(e0 + e1);
        if (lane == 0) smem[516 + wid] = s;
        __syncthreads();
        if (t == 0) smem[521] = smem[516] + smem[517] + smem[518] + smem[519];
        __syncthreads();
        float inv = 1.f / smem[521];
        float w0 = e0 * inv, w1 = e1 * inv;
        smem[t] = w0;
        smem[t + 256] = w1;
        if (blockIdx.x == 0) { out[OUT_AW + t] = w0; out[OUT_AW + t + 256] = w1; }
        __syncthreads();
        int jc = blockIdx.x & 3, lc = blockIdx.x >> 2;
        int j = jc * 256 + t;
        int l0 = lc * 64;
        float acc = 0.f;
        for (int l = l0; l < l0 + 64; ++l) acc += smem[l] * enc[(size_t)l * H + j];
        atomicAdd(&ws[WS_X + E + j], acc);
    }
    grid.sync();

    // ---- S4: gi = x @ W_ih^T + b_ih (waves 0..3071) ----
    if (gwave < 3 * H) {
        const float4* x4 = (const float4*)(ws + WS_X);
        const float4* w4 = (const float4*)(W_ih + (size_t)gwave * (E + H));
        float acc = 0.f;
        for (int i = lane; i < (E + H) / 4; i += 64) acc += dot4(x4[i], w4[i]);
        acc = wave_sum(acc);
        if (lane == 0) ws[WS_GI + gwave] = acc + b_ih[gwave];
    }
    grid.sync();

    // ---- S5: GRU combine -> h_new (blocks 0..3) ----
    if (blockIdx.x < 4) {
        int k = blockIdx.x * 256 + t;
        float gir = ws[WS_GI + k],         ghr = ws[WS_GH + k];
        float giz = ws[WS_GI + H + k],     ghz = ws[WS_GH + H + k];
        float gin = ws[WS_GI + 2 * H + k], ghn = ws[WS_GH + 2 * H + k];
        float r = 1.f / (1.f + expf(-(gir + ghr)));
        float z = 1.f / (1.f + expf(-(giz + ghz)));
        float n = tanhf(gin + r * ghn);
        float hn = (1.f - z) * n + z * hidden[k];
        ws[WS_HN + k] = hn;
        out[OUT_H + k] = hn;
    }
    grid.sync();

    // ---- S6: logits + per-block online (max, sumexp) ----
    {
        for (int i = t; i < H; i += 256) smem[i] = ws[WS_HN + i];
        __syncthreads();
        const float4* hn4 = (const float4*)smem;
        float m = -INFINITY, s = 0.f;
        for (int row = gwave; row < V; row += 4 * NBLK) {
            const float4* w4 = (const float4*)(out_W + (size_t)row * H);
            float acc = 0.f;
            for (int i = lane; i < H / 4; i += 64) acc += dot4(hn4[i], w4[i]);
            acc = wave_sum(acc);
            if (lane == 0) {
                float lg = acc + out_b[row];
                out[row] = lg;
                if (lg > m) { s = s * expf(m - lg) + 1.f; m = lg; }
                else        { s += expf(lg - m); }
            }
        }
        if (lane == 0) { smem[1024 + wid] = m; smem[1028 + wid] = s; }
        __syncthreads();
        if (t == 0) {
            float M = fmaxf(fmaxf(smem[1024], smem[1025]), fmaxf(smem[1026], smem[1027]));
            float S = smem[1028] * expf(smem[1024] - M) + smem[1029] * expf(smem[1025] - M)
                    + smem[1030] * expf(smem[1026] - M) + smem[1031] * expf(smem[1027] - M);
            ws[WS_BM + blockIdx.x] = M;
            ws[WS_BS + blockIdx.x] = S;
        }
    }
    grid.sync();

    // ---- S7: combine 1024 (max,sum) pairs -> logsumexp offset (block 0) ----
    if (blockIdx.x == 0) {
        float m = -INFINITY, s = 0.f;
        for (int b = t; b < NBLK; b += 256) {
            float bm = ws[WS_BM + b], bs = ws[WS_BS + b];
            float M2 = fmaxf(m, bm);
            s = s * expf(m - M2) + bs * expf(bm - M2);
            m = M2;
        }
        for (int off = 32; off > 0; off >>= 1) {
            float mo = __shfl_down(m, off, 64);
            float so = __shfl_down(s, off, 64);
            float M2 = fmaxf(m, mo);
            s = s * expf(m - M2) + so * expf(mo - M2);
            m = M2;
        }
        if (lane == 0) { smem[wid] = m; smem[4 + wid] = s; }
        __syncthreads();
        if (t == 0) {
            float M = smem[0], S = smem[4];
            for (int i = 1; i < 4; i++) {
                float M2 = fmaxf(M, smem[i]);
                S = S * expf(M - M2) + smem[4 + i] * expf(smem[i] - M2);
                M = M2;
            }
            ws[WS_OFF] = M + logf(S);
        }
    }
    grid.sync();

    // ---- S8: log_probs = logit - offset ----
    {
        float off = ws[WS_OFF];
        int i = blockIdx.x * 256 + t;
        if (i < V) out[i] -= off;
    }
}

extern "C" void kernel_launch(void* const* d_in, const int* in_sizes, int n_in,
                              void* d_out, int out_size, void* d_ws, size_t ws_size,
                              hipStream_t stream) {
    const int*   input   = (const int*)d_in[0];
    const float* hidden  = (const float*)d_in[1];
    const float* enc     = (const float*)d_in[2];
    const float* emb     = (const float*)d_in[3];
    const float* attn_W  = (const float*)d_in[4];
    const float* attn_b  = (const float*)d_in[5];
    const float* W_ih    = (const float*)d_in[6];
    const float* W_hh    = (const float*)d_in[7];
    const float* b_ih    = (const float*)d_in[8];
    const float* b_hh    = (const float*)d_in[9];
    const float* out_W   = (const float*)d_in[10];
    const float* out_b   = (const float*)d_in[11];
    float* out = (float*)d_out;
    float* ws  = (float*)d_ws;

    void* args[] = {
        (void*)&input, (void*)&hidden, (void*)&enc, (void*)&emb,
        (void*)&attn_W, (void*)&attn_b, (void*)&W_ih, (void*)&W_hh,
        (void*)&b_ih, (void*)&b_hh, (void*)&out_W, (void*)&out_b,
        (void*)&out, (void*)&ws
    };
    hipLaunchCooperativeKernel((void*)mega, dim3(NBLK), dim3(256), args, 0, stream);
}

// Round 3
// 442.164 us; speedup vs baseline: 2.3717x; 2.3717x over previous
//
#include <hip/hip_runtime.h>
#include <math.h>

#define V 50257
#define E 1024
#define H 1024
#define L 512

// d_out offsets (floats): [log_probs V][h_new H][attn_weights L]
#define OUT_H  50257
#define OUT_AW 51281

// ws offsets (floats)
#define WS_S    0       // 512 attn scores
#define WS_X    1024    // 2048 x = [embedded, attn_applied]
#define WS_GH   3072    // 3072 gh
#define WS_GI   6144    // 3072 gi
#define WS_BM   10240   // 2048 per-block maxes
#define WS_BS   12288   // 2048 per-block sumexps

__device__ __forceinline__ float dot4(const float4 a, const float4 b) {
    return a.x * b.x + a.y * b.y + a.z * b.z + a.w * b.w;
}

__device__ __forceinline__ float wave_sum(float v) {
    for (int off = 32; off > 0; off >>= 1) v += __shfl_down(v, off, 64);
    return v;
}

// K1: attn scores (waves 0..511) + gh (512..3583) + zero x[E:] (3584..3599)
//     + stage emb into x[0:E] (3600..3615).  904 blocks x 256.
__global__ void k1_scores_gh(const int* __restrict__ input,
                             const float* __restrict__ hidden,
                             const float* __restrict__ emb_table,
                             const float* __restrict__ attn_W,
                             const float* __restrict__ attn_b,
                             const float* __restrict__ W_hh,
                             const float* __restrict__ b_hh,
                             float* __restrict__ ws) {
    const int t = threadIdx.x;
    const int lane = t & 63;
    const int gwave = blockIdx.x * 4 + (t >> 6);
    const float4* h4 = (const float4*)hidden;
    const float* embrow = emb_table + (size_t)input[0] * E;

    if (gwave < L) {
        const float4* emb4 = (const float4*)embrow;
        const float4* w4 = (const float4*)(attn_W + (size_t)gwave * (E + H));
        float acc = 0.f;
#pragma unroll
        for (int k = 0; k < 8; ++k) {
            int i = lane + 64 * k;
            float4 a = (k < 4) ? emb4[i] : h4[i - E / 4];
            acc += dot4(a, w4[i]);
        }
        acc = wave_sum(acc);
        if (lane == 0) ws[WS_S + gwave] = acc + attn_b[gwave];
    } else if (gwave < L + 3 * H) {
        int k = gwave - L;
        const float4* w4 = (const float4*)(W_hh + (size_t)k * H);
        float acc = 0.f;
#pragma unroll
        for (int ii = 0; ii < 4; ++ii) {
            int i = lane + 64 * ii;
            acc += dot4(h4[i], w4[i]);
        }
        acc = wave_sum(acc);
        if (lane == 0) ws[WS_GH + k] = acc + b_hh[k];
    } else if (gwave < 3600) {          // zero attn_applied accumulator
        ws[WS_X + E + (gwave - 3584) * 64 + lane] = 0.f;
    } else if (gwave < 3616) {          // stage embedded into x[0:E]
        int i = (gwave - 3600) * 64 + lane;
        ws[WS_X + i] = embrow[i];
    }
}

// K2: redundant per-block softmax over 512 scores, then attn_applied slice.
//     32 blocks x 256: jc = blk&3 (j-chunk of 256), lc = blk>>2 (l-chunk of 64).
__global__ void k2_softmax_applied(const float* __restrict__ enc,
                                   float* __restrict__ ws,
                                   float* __restrict__ out) {
    __shared__ float w[512];
    __shared__ float redm[4], reds[4];
    __shared__ float bmax, bsum;
    const int t = threadIdx.x;
    const int lane = t & 63, wid = t >> 6;

    float v0 = ws[WS_S + t];
    float v1 = ws[WS_S + 256 + t];
    float m = fmaxf(v0, v1);
    for (int off = 32; off > 0; off >>= 1) m = fmaxf(m, __shfl_down(m, off, 64));
    if (lane == 0) redm[wid] = m;
    __syncthreads();
    if (t == 0) bmax = fmaxf(fmaxf(redm[0], redm[1]), fmaxf(redm[2], redm[3]));
    __syncthreads();
    float e0 = expf(v0 - bmax), e1 = expf(v1 - bmax);
    float s = wave_sum(e0 + e1);
    if (lane == 0) reds[wid] = s;
    __syncthreads();
    if (t == 0) bsum = reds[0] + reds[1] + reds[2] + reds[3];
    __syncthreads();
    float inv = 1.f / bsum;
    w[t] = e0 * inv;
    w[256 + t] = e1 * inv;
    if (blockIdx.x == 0) {
        out[OUT_AW + t] = e0 * inv;
        out[OUT_AW + 256 + t] = e1 * inv;
    }
    __syncthreads();

    const int j = (blockIdx.x & 3) * 256 + t;
    const int l0 = (blockIdx.x >> 2) * 64;
    float acc = 0.f;
#pragma unroll 8
    for (int l = l0; l < l0 + 64; ++l)
        acc += w[l] * enc[(size_t)l * H + j];
    atomicAdd(&ws[WS_X + E + j], acc);
}

// K3: gi = x @ W_ih^T + b_ih; one wave per row, 768 blocks x 256.
__global__ void k3_gi(const float* __restrict__ W_ih, const float* __restrict__ b_ih,
                      float* __restrict__ ws) {
    const int lane = threadIdx.x & 63;
    const int gwave = blockIdx.x * 4 + (threadIdx.x >> 6);
    const float4* x4 = (const float4*)(ws + WS_X);
    const float4* w4 = (const float4*)(W_ih + (size_t)gwave * (E + H));
    float acc = 0.f;
#pragma unroll
    for (int k = 0; k < 8; ++k) {
        int i = lane + 64 * k;
        acc += dot4(x4[i], w4[i]);
    }
    acc = wave_sum(acc);
    if (lane == 0) ws[WS_GI + gwave] = acc + b_ih[gwave];
}

// K4: redundant h_new per block -> LDS, then logits + per-block online (max,sumexp).
//     2048 blocks x 256 (8 blocks/CU). Block 0 writes h_new to out.
__global__ void k4_logits(const float* __restrict__ hidden,
                          const float* __restrict__ out_W,
                          const float* __restrict__ out_b,
                          float* __restrict__ ws,
                          float* __restrict__ out) {
    __shared__ float hn[H];
    __shared__ float wm[4], wsum[4];
    const int t = threadIdx.x;
    const int lane = t & 63, wid = t >> 6;

    // h_new computed redundantly (gi/gh/hidden are L2-hot, 28 KB)
#pragma unroll
    for (int c = 0; c < 4; ++c) {
        int k = t + 256 * c;
        float gir = ws[WS_GI + k],         ghr = ws[WS_GH + k];
        float giz = ws[WS_GI + H + k],     ghz = ws[WS_GH + H + k];
        float gin = ws[WS_GI + 2 * H + k], ghn = ws[WS_GH + 2 * H + k];
        float r = 1.f / (1.f + expf(-(gir + ghr)));
        float z = 1.f / (1.f + expf(-(giz + ghz)));
        float n = tanhf(gin + r * ghn);
        float v = (1.f - z) * n + z * hidden[k];
        hn[k] = v;
        if (blockIdx.x == 0) out[OUT_H + k] = v;
    }
    __syncthreads();

    const float4* hn4 = (const float4*)hn;
    const int gwave = blockIdx.x * 4 + wid;
    float m = -INFINITY, s = 0.f;
    for (int row = gwave; row < V; row += 8192) {
        const float4* w4 = (const float4*)(out_W + (size_t)row * H);
        float acc = 0.f;
#pragma unroll
        for (int ii = 0; ii < 4; ++ii) {
            int i = lane + 64 * ii;
            acc += dot4(hn4[i], w4[i]);
        }
        acc = wave_sum(acc);
        if (lane == 0) {
            float lg = acc + out_b[row];
            out[row] = lg;
            if (lg > m) { s = s * expf(m - lg) + 1.f; m = lg; }
            else        { s += expf(lg - m); }
        }
    }
    if (lane == 0) { wm[wid] = m; wsum[wid] = s; }
    __syncthreads();
    if (t == 0) {
        float M = fmaxf(fmaxf(wm[0], wm[1]), fmaxf(wm[2], wm[3]));
        float S = wsum[0] * expf(wm[0] - M) + wsum[1] * expf(wm[1] - M)
                + wsum[2] * expf(wm[2] - M) + wsum[3] * expf(wm[3] - M);
        ws[WS_BM + blockIdx.x] = M;
        ws[WS_BS + blockIdx.x] = S;
    }
}

// K5: each block redundantly combines the 2048 (m,s) pairs (16 KB, L2-hot),
//     then subtracts the logsumexp offset from its 256 logits. 197 blocks.
__global__ void k5_logprobs(const float* __restrict__ ws, float* __restrict__ out) {
    __shared__ float redm[4], reds[4];
    __shared__ float off_s;
    const int t = threadIdx.x;
    const int lane = t & 63, wid = t >> 6;
    float m = -INFINITY, s = 0.f;
#pragma unroll
    for (int c = 0; c < 8; ++c) {
        int b = t + 256 * c;
        float bm = ws[WS_BM + b], bs = ws[WS_BS + b];
        float M2 = fmaxf(m, bm);
        s = s * expf(m - M2) + bs * expf(bm - M2);
        m = M2;
    }
    for (int off = 32; off > 0; off >>= 1) {
        float mo = __shfl_down(m, off, 64);
        float so = __shfl_down(s, off, 64);
        float M2 = fmaxf(m, mo);
        s = s * expf(m - M2) + so * expf(mo - M2);
        m = M2;
    }
    if (lane == 0) { redm[wid] = m; reds[wid] = s; }
    __syncthreads();
    if (t == 0) {
        float M = redm[0], S = reds[0];
        for (int i = 1; i < 4; ++i) {
            float M2 = fmaxf(M, redm[i]);
            S = S * expf(M - M2) + reds[i] * expf(redm[i] - M2);
            M = M2;
        }
        off_s = M + logf(S);
    }
    __syncthreads();
    int i = blockIdx.x * 256 + t;
    if (i < V) out[i] -= off_s;
}

extern "C" void kernel_launch(void* const* d_in, const int* in_sizes, int n_in,
                              void* d_out, int out_size, void* d_ws, size_t ws_size,
                              hipStream_t stream) {
    const int*   input   = (const int*)d_in[0];
    const float* hidden  = (const float*)d_in[1];
    const float* enc     = (const float*)d_in[2];
    const float* emb     = (const float*)d_in[3];
    const float* attn_W  = (const float*)d_in[4];
    const float* attn_b  = (const float*)d_in[5];
    const float* W_ih    = (const float*)d_in[6];
    const float* W_hh    = (const float*)d_in[7];
    const float* b_ih    = (const float*)d_in[8];
    const float* b_hh    = (const float*)d_in[9];
    const float* out_W   = (const float*)d_in[10];
    const float* out_b   = (const float*)d_in[11];
    float* out = (float*)d_out;
    float* ws  = (float*)d_ws;

    k1_scores_gh<<<904, 256, 0, stream>>>(input, hidden, emb, attn_W, attn_b, W_hh, b_hh, ws);
    k2_softmax_applied<<<32, 256, 0, stream>>>(enc, ws, out);
    k3_gi<<<768, 256, 0, stream>>>(W_ih, b_ih, ws);
    k4_logits<<<2048, 256, 0, stream>>>(hidden, out_W, out_b, ws, out);
    k5_logprobs<<<197, 256, 0, stream>>>(ws, out);
}